// Round 8
// baseline (169.323 us; speedup 1.0000x reference)
//
#include <hip/hip_runtime.h>
#include <hip/hip_bf16.h>

// Fastfood transform, LL = 2^23, d = 1024.
// out = FWHT_LL( GG * (FWHT_LL(BB .* pad(x)))[Pi] )
// FWHT_LL of a vector supported on [0,1024) is w[i & 1023],
// w = FWHT_1024(BB[:1024] * x)  (recomputed per block, 4 KB LDS).
// Second FWHT: bits 0..13 in-chunk (k_low), bits 14..22 cross-chunk
// (k_high). bf16 intermediate in d_ws. All butterflies in registers.
// R5 lesson: hipLaunchCooperativeKernel does NOT survive graph capture.
// R6 lesson: without __launch_bounds__(256,2) the backend caps VGPRs (~68)
// and spills v[]/nv[] to scratch -> latency death.
// R8 PROBE: kernels launched TWICE (idempotent) to measure their true
// total duration as dur_us - 137.8, since sub-41us dispatches are
// invisible behind the harness's fillBuffer rows in the top-5 counters.

#define NC 16384
#define TRPAD 260              // 32 rows * 260 floats, conflict-free transpose

__device__ __forceinline__ void fwht64(float* v) {
  #pragma unroll
  for (int s = 0; s < 6; ++s) {
    const int d = 1 << s;
    #pragma unroll
    for (int jj = 0; jj < 64; ++jj) {
      if ((jj & d) == 0) {
        float a = v[jj], b = v[jj + d];
        v[jj]     = a + b;
        v[jj + d] = a - b;
      }
    }
  }
}

// ---------------- k_low: gather/scale + FWHT over bits 0..13 ----------------
__global__ __launch_bounds__(256, 2) void k_low(
    const float* __restrict__ x, const float* __restrict__ BB,
    const int* __restrict__ Pi, const float* __restrict__ GG,
    __hip_bfloat16* __restrict__ mid)
{
  __shared__ float w[1024];
  __shared__ float tr[32 * TRPAD];
  const int t = threadIdx.x;
  const long base = (long)blockIdx.x * NC;

  // Ownership A: i = (t>>2)<<8 | q<<4 | (t&3)<<2 | e   [j = 4q+e]
  const int4*   Pi4 = (const int4*)(Pi + base);
  const float4* GG4 = (const float4*)(GG + base);
  const int vb = (t >> 2) * 64 + (t & 3);

  // hoist ALL global loads (16 int4 + 16 float4): latency hides under the
  // w-prologue's 9 barrier stages below
  int4 p[16];
  #pragma unroll
  for (int q = 0; q < 16; ++q) p[q] = Pi4[vb + 4 * q];
  float v[64];
  #pragma unroll
  for (int q = 0; q < 16; ++q) {
    float4 g = GG4[vb + 4 * q];
    v[4 * q + 0] = g.x; v[4 * q + 1] = g.y;
    v[4 * q + 2] = g.z; v[4 * q + 3] = g.w;
  }

  // ---- w = FWHT_1024(BB[:1024] * x) ----
  {
    float4 xx = ((const float4*)x)[t];
    float4 bb = ((const float4*)BB)[t];
    float a0 = xx.x * bb.x, a1 = xx.y * bb.y, a2 = xx.z * bb.z, a3 = xx.w * bb.w;
    float b0 = a0 + a1, b1 = a0 - a1, b2 = a2 + a3, b3 = a2 - a3;
    w[4 * t + 0] = b0 + b2; w[4 * t + 1] = b1 + b3;
    w[4 * t + 2] = b0 - b2; w[4 * t + 3] = b1 - b3;
  }
  __syncthreads();
  #pragma unroll
  for (int s = 2; s <= 9; ++s) {
    const int h = 1 << s;
    #pragma unroll
    for (int k2 = 0; k2 < 2; ++k2) {
      int jb = k2 * 256 + t;
      int i0 = ((jb >> s) << (s + 1)) | (jb & (h - 1));
      float aa = w[i0], bv = w[i0 + h];
      w[i0] = aa + bv; w[i0 + h] = aa - bv;
    }
    __syncthreads();
  }

  // ---- gather + scale (GG already in v) ----
  #pragma unroll
  for (int q = 0; q < 16; ++q) {
    v[4 * q + 0] *= w[p[q].x & 1023];
    v[4 * q + 1] *= w[p[q].y & 1023];
    v[4 * q + 2] *= w[p[q].z & 1023];
    v[4 * q + 3] *= w[p[q].w & 1023];
  }

  fwht64(v);                                       // i bits 0,1,4,5,6,7

  #pragma unroll
  for (int jj = 0; jj < 64; ++jj) {                // i bit 2 (lane bit 0)
    float u = __shfl_xor(v[jj], 1);
    v[jj] = (t & 1) ? (u - v[jj]) : (v[jj] + u);
  }
  #pragma unroll
  for (int jj = 0; jj < 64; ++jj) {                // i bit 3 (lane bit 1)
    float u = __shfl_xor(v[jj], 2);
    v[jj] = (t & 2) ? (u - v[jj]) : (v[jj] + u);
  }

  // ---- LDS transpose to ownership B: i = j2*256 + t ----
  float nv[64];
  #pragma unroll
  for (int r = 0; r < 2; ++r) {
    if (r == 1) __syncthreads();
    #pragma unroll
    for (int jl = 0; jl < 32; ++jl)
      tr[jl * TRPAD + t] = v[r * 32 + jl];
    __syncthreads();
    if ((t >> 7) == r) {                           // wave-uniform
      const int jl = (((t >> 4) << 2) | (t & 3)) & 31;
      const int cc = (t >> 2) & 3;
      #pragma unroll
      for (int j2 = 0; j2 < 64; ++j2)
        nv[j2] = tr[jl * TRPAD + j2 * 4 + cc];
    }
  }

  fwht64(nv);                                      // i bits 8..13

  #pragma unroll
  for (int j2 = 0; j2 < 64; ++j2)                  // coalesced bf16 stores
    mid[base + j2 * 256 + t] = __float2bfloat16(nv[j2]);
}

// ---------------- k_high: FWHT over bits 14..22 ----------------
// View mid as [512 rows][16384 cols]; block owns 32 cols x all 512 rows.
__global__ __launch_bounds__(256, 2) void k_high(
    const __hip_bfloat16* __restrict__ mid, float* __restrict__ out)
{
  __shared__ float tr[32 * TRPAD];
  const int t = threadIdx.x;
  const long cb = (long)blockIdx.x * 32;
  const int c = t & 31;
  const int g2 = t >> 5;

  float v[64];
  #pragma unroll
  for (int j = 0; j < 64; ++j)
    v[j] = __bfloat162float(mid[(long)(j * 8 + g2) * NC + cb + c]);

  fwht64(v);                                       // row bits 3..8

  float nv[64];
  #pragma unroll
  for (int r = 0; r < 2; ++r) {
    if (r == 1) __syncthreads();
    #pragma unroll
    for (int jl = 0; jl < 32; ++jl)
      tr[jl * TRPAD + t] = v[r * 32 + jl];
    __syncthreads();
    if ((t >> 7) == r) {
      #pragma unroll
      for (int j2 = 0; j2 < 64; ++j2) {
        int jl = ((g2 & 3) * 8) + (j2 >> 3);
        nv[j2] = tr[jl * TRPAD + ((j2 & 7) << 5) + c];
      }
    }
  }

  #pragma unroll
  for (int s = 0; s < 3; ++s) {                    // row bits 0..2
    const int d = 1 << s;
    #pragma unroll
    for (int jj = 0; jj < 64; ++jj) {
      if ((jj & d) == 0) {
        float a = nv[jj], b = nv[jj + d];
        nv[jj]     = a + b;
        nv[jj + d] = a - b;
      }
    }
  }

  #pragma unroll
  for (int j2 = 0; j2 < 64; ++j2)
    out[(long)(g2 * 64 + j2) * NC + cb + c] = nv[j2];
}

extern "C" void kernel_launch(void* const* d_in, const int* in_sizes, int n_in,
                              void* d_out, int out_size, void* d_ws, size_t ws_size,
                              hipStream_t stream) {
  const float* x  = (const float*)d_in[0];   // (1024,) f32
  const float* BB = (const float*)d_in[1];   // (LL,)   f32, only [:1024] used
  const float* GG = (const float*)d_in[2];   // (LL,)   f32
  const int*   Pi = (const int*)  d_in[3];   // (LL,)   i32 permutation
  float* out = (float*)d_out;                // (LL,)   f32
  __hip_bfloat16* mid = (__hip_bfloat16*)d_ws;  // 16 MB bf16 intermediate

  // R8 measurement probe: run the pipeline twice (idempotent, identical
  // writes). T_kernels = dur_us - 137.8 (the R7 single-run baseline).
  k_low<<<512, 256, 0, stream>>>(x, BB, Pi, GG, mid);
  k_high<<<512, 256, 0, stream>>>(mid, out);
  k_low<<<512, 256, 0, stream>>>(x, BB, Pi, GG, mid);
  k_high<<<512, 256, 0, stream>>>(mid, out);
}

// Round 9
// 137.313 us; speedup vs baseline: 1.2331x; 1.2331x over previous
//
#include <hip/hip_runtime.h>
#include <hip/hip_bf16.h>

// Fastfood transform, LL = 2^23, d = 1024.
// out = FWHT_LL( GG * (FWHT_LL(BB .* pad(x)))[Pi] )
// FWHT_LL of a vector supported on [0,1024) is w[i & 1023],
// w = FWHT_1024(BB[:1024] * x)  (recomputed per block, 4 KB LDS).
// Second FWHT: bits 0..13 in-chunk (k_low), bits 14..22 cross-chunk
// (k_high). bf16 intermediate in d_ws. All butterflies in registers.
// R5 lesson: hipLaunchCooperativeKernel does NOT survive graph capture.
// R6 lesson: without __launch_bounds__(256,2) the backend caps VGPRs (~68)
// and spills v[]/nv[] to scratch.
// R8 probe result: pipeline (k_low+k_high) = 31.5 us; the remaining ~106 us
// of dur_us is harness reset traffic (two ~268 MB 0xAA poison fills + d_in
// restore) — not controllable from kernel_launch. Kernels are within ~20%
// of their ~26-30 us mixed-L3/HBM traffic + launch-overhead floor.

#define NC 16384
#define TRPAD 260              // 32 rows * 260 floats, conflict-free transpose

__device__ __forceinline__ void fwht64(float* v) {
  #pragma unroll
  for (int s = 0; s < 6; ++s) {
    const int d = 1 << s;
    #pragma unroll
    for (int jj = 0; jj < 64; ++jj) {
      if ((jj & d) == 0) {
        float a = v[jj], b = v[jj + d];
        v[jj]     = a + b;
        v[jj + d] = a - b;
      }
    }
  }
}

// ---------------- k_low: gather/scale + FWHT over bits 0..13 ----------------
__global__ __launch_bounds__(256, 2) void k_low(
    const float* __restrict__ x, const float* __restrict__ BB,
    const int* __restrict__ Pi, const float* __restrict__ GG,
    __hip_bfloat16* __restrict__ mid)
{
  __shared__ float w[1024];
  __shared__ float tr[32 * TRPAD];
  const int t = threadIdx.x;
  const long base = (long)blockIdx.x * NC;

  // Ownership A: i = (t>>2)<<8 | q<<4 | (t&3)<<2 | e   [j = 4q+e]
  const int4*   Pi4 = (const int4*)(Pi + base);
  const float4* GG4 = (const float4*)(GG + base);
  const int vb = (t >> 2) * 64 + (t & 3);

  // hoist ALL global loads (16 int4 + 16 float4): latency hides under the
  // w-prologue's 9 barrier stages below
  int4 p[16];
  #pragma unroll
  for (int q = 0; q < 16; ++q) p[q] = Pi4[vb + 4 * q];
  float v[64];
  #pragma unroll
  for (int q = 0; q < 16; ++q) {
    float4 g = GG4[vb + 4 * q];
    v[4 * q + 0] = g.x; v[4 * q + 1] = g.y;
    v[4 * q + 2] = g.z; v[4 * q + 3] = g.w;
  }

  // ---- w = FWHT_1024(BB[:1024] * x) ----
  {
    float4 xx = ((const float4*)x)[t];
    float4 bb = ((const float4*)BB)[t];
    float a0 = xx.x * bb.x, a1 = xx.y * bb.y, a2 = xx.z * bb.z, a3 = xx.w * bb.w;
    float b0 = a0 + a1, b1 = a0 - a1, b2 = a2 + a3, b3 = a2 - a3;
    w[4 * t + 0] = b0 + b2; w[4 * t + 1] = b1 + b3;
    w[4 * t + 2] = b0 - b2; w[4 * t + 3] = b1 - b3;
  }
  __syncthreads();
  #pragma unroll
  for (int s = 2; s <= 9; ++s) {
    const int h = 1 << s;
    #pragma unroll
    for (int k2 = 0; k2 < 2; ++k2) {
      int jb = k2 * 256 + t;
      int i0 = ((jb >> s) << (s + 1)) | (jb & (h - 1));
      float aa = w[i0], bv = w[i0 + h];
      w[i0] = aa + bv; w[i0 + h] = aa - bv;
    }
    __syncthreads();
  }

  // ---- gather + scale (GG already in v) ----
  #pragma unroll
  for (int q = 0; q < 16; ++q) {
    v[4 * q + 0] *= w[p[q].x & 1023];
    v[4 * q + 1] *= w[p[q].y & 1023];
    v[4 * q + 2] *= w[p[q].z & 1023];
    v[4 * q + 3] *= w[p[q].w & 1023];
  }

  fwht64(v);                                       // i bits 0,1,4,5,6,7

  #pragma unroll
  for (int jj = 0; jj < 64; ++jj) {                // i bit 2 (lane bit 0)
    float u = __shfl_xor(v[jj], 1);
    v[jj] = (t & 1) ? (u - v[jj]) : (v[jj] + u);
  }
  #pragma unroll
  for (int jj = 0; jj < 64; ++jj) {                // i bit 3 (lane bit 1)
    float u = __shfl_xor(v[jj], 2);
    v[jj] = (t & 2) ? (u - v[jj]) : (v[jj] + u);
  }

  // ---- LDS transpose to ownership B: i = j2*256 + t ----
  float nv[64];
  #pragma unroll
  for (int r = 0; r < 2; ++r) {
    if (r == 1) __syncthreads();
    #pragma unroll
    for (int jl = 0; jl < 32; ++jl)
      tr[jl * TRPAD + t] = v[r * 32 + jl];
    __syncthreads();
    if ((t >> 7) == r) {                           // wave-uniform
      const int jl = (((t >> 4) << 2) | (t & 3)) & 31;
      const int cc = (t >> 2) & 3;
      #pragma unroll
      for (int j2 = 0; j2 < 64; ++j2)
        nv[j2] = tr[jl * TRPAD + j2 * 4 + cc];
    }
  }

  fwht64(nv);                                      // i bits 8..13

  #pragma unroll
  for (int j2 = 0; j2 < 64; ++j2)                  // coalesced bf16 stores
    mid[base + j2 * 256 + t] = __float2bfloat16(nv[j2]);
}

// ---------------- k_high: FWHT over bits 14..22 ----------------
// View mid as [512 rows][16384 cols]; block owns 32 cols x all 512 rows.
__global__ __launch_bounds__(256, 2) void k_high(
    const __hip_bfloat16* __restrict__ mid, float* __restrict__ out)
{
  __shared__ float tr[32 * TRPAD];
  const int t = threadIdx.x;
  const long cb = (long)blockIdx.x * 32;
  const int c = t & 31;
  const int g2 = t >> 5;

  float v[64];
  #pragma unroll
  for (int j = 0; j < 64; ++j)
    v[j] = __bfloat162float(mid[(long)(j * 8 + g2) * NC + cb + c]);

  fwht64(v);                                       // row bits 3..8

  float nv[64];
  #pragma unroll
  for (int r = 0; r < 2; ++r) {
    if (r == 1) __syncthreads();
    #pragma unroll
    for (int jl = 0; jl < 32; ++jl)
      tr[jl * TRPAD + t] = v[r * 32 + jl];
    __syncthreads();
    if ((t >> 7) == r) {
      #pragma unroll
      for (int j2 = 0; j2 < 64; ++j2) {
        int jl = ((g2 & 3) * 8) + (j2 >> 3);
        nv[j2] = tr[jl * TRPAD + ((j2 & 7) << 5) + c];
      }
    }
  }

  #pragma unroll
  for (int s = 0; s < 3; ++s) {                    // row bits 0..2
    const int d = 1 << s;
    #pragma unroll
    for (int jj = 0; jj < 64; ++jj) {
      if ((jj & d) == 0) {
        float a = nv[jj], b = nv[jj + d];
        nv[jj]     = a + b;
        nv[jj + d] = a - b;
      }
    }
  }

  #pragma unroll
  for (int j2 = 0; j2 < 64; ++j2)
    out[(long)(g2 * 64 + j2) * NC + cb + c] = nv[j2];
}

extern "C" void kernel_launch(void* const* d_in, const int* in_sizes, int n_in,
                              void* d_out, int out_size, void* d_ws, size_t ws_size,
                              hipStream_t stream) {
  const float* x  = (const float*)d_in[0];   // (1024,) f32
  const float* BB = (const float*)d_in[1];   // (LL,)   f32, only [:1024] used
  const float* GG = (const float*)d_in[2];   // (LL,)   f32
  const int*   Pi = (const int*)  d_in[3];   // (LL,)   i32 permutation
  float* out = (float*)d_out;                // (LL,)   f32
  __hip_bfloat16* mid = (__hip_bfloat16*)d_ws;  // 16 MB bf16 intermediate

  k_low<<<512, 256, 0, stream>>>(x, BB, Pi, GG, mid);
  k_high<<<512, 256, 0, stream>>>(mid, out);
}